// Round 2
// baseline (251.615 us; speedup 1.0000x reference)
//
#include <hip/hip_runtime.h>
#include <cstdint>
#include <cstddef>

using u16 = unsigned short;
using u32 = unsigned int;
using u64 = unsigned long long;

typedef short bf16x8 __attribute__((ext_vector_type(8)));
typedef float f32x4 __attribute__((ext_vector_type(4)));

constexpr int N0 = 8192;
constexpr int N1 = 4096;
constexpr int N2 = 2048;
constexpr int COUT = 128;
constexpr int KNB = 16;

// x-bucket sort parameters: monotone u32 key, top 13 bits = bucket (sign+exp+4 mantissa)
constexpr int BSHIFT = 19;
constexpr int NBUCK = 8192;               // 2^(32-19)
constexpr u32 BMASK = 0xFFF80000u;        // bucket floor mask
constexpr u32 BINC  = 0x00080000u;        // one bucket

__device__ __forceinline__ float bf2f(u16 v) { return __uint_as_float(((u32)v) << 16); }
__device__ __forceinline__ u16 f2bf(float f) {  // round-to-nearest-even
    u32 u = __float_as_uint(f);
    return (u16)((u + 0x7fffu + ((u >> 16) & 1u)) >> 16);
}
__device__ __forceinline__ void cvt8(const float* __restrict__ src, u16* __restrict__ dst, int e) {
    float t0[8];
    *(float4*)t0 = *(const float4*)(src + e);
    *(float4*)(t0 + 4) = *(const float4*)(src + e + 4);
    u16 o[8];
#pragma unroll
    for (int q = 0; q < 8; ++q) o[q] = f2bf(t0[q]);
    *(uint4*)(dst + e) = *(uint4*)o;
}

// Distances must match the np reference bit-exactly: no FMA contraction, sequential sum.
__device__ __forceinline__ float dist2s(float cx, float cy, float cz,
                                        float px, float py, float pz) {
#pragma clang fp contract(off)
    float dx = cx - px;
    float dy = cy - py;
    float dz = cz - pz;
    float s = dx * dx;
    s = s + dy * dy;
    s = s + dz * dz;
    return s;
}

// monotone u32 of float bits (strictly increasing in float order, non-NaN)
__device__ __forceinline__ u32 monot(u32 u) {
    return (u & 0x80000000u) ? ~u : (u | 0x80000000u);
}
// inverse of monotone transform (valid for any bucket-boundary key)
__device__ __forceinline__ float invmono(u32 k) {
    return (k & 0x80000000u) ? __uint_as_float(k & 0x7FFFFFFFu) : __uint_as_float(~k);
}

// ---- DPP cross-lane helpers (VALU pipe, no LDS traffic) ----
template <int CTRL>
__device__ __forceinline__ u64 dpp64(u64 v) {
    int lo = (int)(u32)v, hi = (int)(u32)(v >> 32);
    int plo = __builtin_amdgcn_update_dpp(0, lo, CTRL, 0xF, 0xF, true);
    int phi = __builtin_amdgcn_update_dpp(0, hi, CTRL, 0xF, 0xF, true);
    return (((u64)(u32)phi) << 32) | (u32)plo;
}
// row_shr:1 with bound_ctrl=1: lane L gets lane L-1; lane 0 of each 16-row gets 0.
__device__ __forceinline__ u64 dpp_prev_u64(u64 v) { return dpp64<0x111>(v); }

__device__ __forceinline__ u32 rdlane(u32 v, int l) {
    return (u32)__builtin_amdgcn_readlane((int)v, l);
}

// ---------------- sort_kernel: per (batch, level) bucket-sort by x ----------------
// Records: uint4 {bits(x), bits(y), bits(z), orig_idx}. rank[orig] = sorted slot.
// Within-bucket order arbitrary (atomic scatter) — pruning uses bucket boundaries only,
// and the top-16 key set is insertion-order independent, so output stays exact.
__global__ __launch_bounds__(256)
void sort_kernel(const float* __restrict__ pos0,
                 uint4* __restrict__ sortedA, u32* __restrict__ rankA,
                 uint4* __restrict__ sortedB, u32* __restrict__ rankB) {
    __shared__ u32 hist[NBUCK];
    __shared__ u32 tot[256];
    int tid = threadIdx.x;
    int b = blockIdx.x >> 1, lvl = blockIdx.x & 1;
    int n = lvl ? 4096 : 8192;
    int pst = lvl ? 6 : 3;
    const float* P = pos0 + (size_t)b * N0 * 3;
    uint4* recs = lvl ? (sortedB + (size_t)b * 4096) : (sortedA + (size_t)b * 8192);
    u32* rank = lvl ? (rankB + (size_t)b * 4096) : (rankA + (size_t)b * 8192);

    for (int i = tid; i < NBUCK; i += 256) hist[i] = 0;
    __syncthreads();
    for (int i = tid; i < n; i += 256) {
        u32 key = monot(__float_as_uint(P[(size_t)i * pst]));
        atomicAdd(&hist[key >> BSHIFT], 1u);
    }
    __syncthreads();
    // exclusive scan of hist (in place): 32 slots/thread in registers, then block scan
    u32 vals[32];
    int base = tid * 32;
#pragma unroll
    for (int j = 0; j < 8; ++j) *(uint4*)&vals[j * 4] = *(uint4*)&hist[base + j * 4];
    u32 run = 0;
#pragma unroll
    for (int j = 0; j < 32; ++j) { u32 c = vals[j]; vals[j] = run; run += c; }
    tot[tid] = run;
    __syncthreads();
    for (int off = 1; off < 256; off <<= 1) {
        u32 v = (tid >= off) ? tot[tid - off] : 0;
        __syncthreads();
        tot[tid] += v;
        __syncthreads();
    }
    u32 add = (tid > 0) ? tot[tid - 1] : 0;
#pragma unroll
    for (int j = 0; j < 32; ++j) vals[j] += add;
#pragma unroll
    for (int j = 0; j < 8; ++j) *(uint4*)&hist[base + j * 4] = *(uint4*)&vals[j * 4];
    __syncthreads();
    // scatter (hist now = running cursor per bucket)
    for (int i = tid; i < n; i += 256) {
        const float* pp = P + (size_t)i * pst;
        float x = pp[0], y = pp[1], z = pp[2];
        u32 key = monot(__float_as_uint(x));
        u32 slot = atomicAdd(&hist[key >> BSHIFT], 1u);
        uint4 r;
        r.x = __float_as_uint(x); r.y = __float_as_uint(y); r.z = __float_as_uint(z);
        r.w = (u32)i;
        recs[slot] = r;
        rank[i] = slot;
    }
}

// ---------------- exact pruned KNN sweep over x-sorted records, 1 center / wave ----
// Sorted-16 list in lanes 0..15 as u64 (d2_bits<<32)|orig_idx — exact order + tie-break.
// Prune proof: d_fp >= fl(dx^2) (non-negative fp addends never round a sum below a
// representable addend); fp subtract & square are monotone; bucket floor/ceil bound x
// of all remaining records on a side. So "fdx>0 && fdx*fdx>cut" pruning is exact.
__device__ __forceinline__ u64 knn_sweep(const uint4* __restrict__ recs, int n,
                                         float cx, float cy, float cz,
                                         int r0, int lane) {
    int wb = r0 - 32;
    if (wb < 0) wb = 0;
    if (wb > n - 64) wb = n - 64;
    u64 key;
    {   // warm start: bitonic-sort the 64 records around the center's rank
        uint4 rec = recs[wb + lane];
        float px = __uint_as_float(rec.x), py = __uint_as_float(rec.y), pz = __uint_as_float(rec.z);
        u64 k = (((u64)__float_as_uint(dist2s(cx, cy, cz, px, py, pz))) << 32) | rec.w;
#pragma unroll
        for (int kk = 2; kk <= 64; kk <<= 1)
#pragma unroll
            for (int jj = kk >> 1; jj > 0; jj >>= 1) {
                u64 o;
                if (jj == 1)      o = dpp64<0xB1>(k);
                else if (jj == 2) o = dpp64<0x4E>(k);
                else if (jj == 8) o = dpp64<0x128>(k);
                else              o = __shfl_xor(k, jj, 64);
                bool keepmin = (((lane & jj) == 0) == ((lane & kk) == 0));
                k = keepmin ? ((o < k) ? o : k) : ((o > k) ? o : k);
            }
        key = k;
    }
    u32 cut = rdlane((u32)(key >> 32), 15);
    float cutf = __uint_as_float(cut);

    int R = wb + 64, L = wb - 64;
    bool rA = (R < n), lA = (L > -64);
    while (rA || lA) {
        if (rA) {
            uint4 rr = recs[min(R + lane, n - 1)];
            // remaining-right x >= bucket floor of lane-0 record
            u32 kb = monot(rdlane(rr.x, 0)) & BMASK;
            float fdx = invmono(kb) - cx;
            if (fdx > 0.f && fdx * fdx > cutf) {
                rA = false;
            } else {
                float px = __uint_as_float(rr.x), py = __uint_as_float(rr.y), pz = __uint_as_float(rr.z);
                u32 d = (R + lane < n) ? __float_as_uint(dist2s(cx, cy, cz, px, py, pz))
                                       : 0xFFFFFFFFu;
                u64 ball = __ballot(d <= cut);
                bool any = ball != 0;
                while (ball) {
                    int src = __ffsll((unsigned long long)ball) - 1;
                    ball &= ball - 1;
                    u64 nk = (((u64)rdlane(d, src)) << 32) | rdlane(rr.w, src);
                    u64 prev = dpp_prev_u64(key);
                    key = (nk < key) ? ((nk < prev) ? prev : nk) : key;
                }
                if (any) { cut = rdlane((u32)(key >> 32), 15); cutf = __uint_as_float(cut); }
                R += 64; rA = (R < n);
            }
        }
        if (lA) {
            uint4 rr = recs[max(L + lane, 0)];
            // remaining-left x < bucket ceil of lane-63 record (max bucket in [0, L+64))
            u32 kb = monot(rdlane(rr.x, 63)) & BMASK;
            bool prune = false;
            if (kb != BMASK) {  // top bucket: can't form ceil, skip prune (never hit in practice)
                float gdx = cx - invmono(kb + BINC);
                prune = (gdx > 0.f && gdx * gdx > cutf);
            }
            if (prune) {
                lA = false;
            } else {
                float px = __uint_as_float(rr.x), py = __uint_as_float(rr.y), pz = __uint_as_float(rr.z);
                u32 d = (L + lane >= 0) ? __float_as_uint(dist2s(cx, cy, cz, px, py, pz))
                                        : 0xFFFFFFFFu;
                u64 ball = __ballot(d <= cut);
                bool any = ball != 0;
                while (ball) {
                    int src = __ffsll((unsigned long long)ball) - 1;
                    ball &= ball - 1;
                    u64 nk = (((u64)rdlane(d, src)) << 32) | rdlane(rr.w, src);
                    u64 prev = dpp_prev_u64(key);
                    key = (nk < key) ? ((nk < prev) ? prev : nk) : key;
                }
                if (any) { cut = rdlane((u32)(key >> 32), 15); cutf = __uint_as_float(cut); }
                L -= 64; lA = (L > -64);
            }
        }
    }
    return key;
}

// ---------------- dispatch 2: knn1 (2048 blk, 1 center/wave) + prep (752 blk) ------
__global__ __launch_bounds__(256)
void knn_prep_kernel(const float* __restrict__ pos0, const float* __restrict__ ch0,
                     const float* __restrict__ W1, const float* __restrict__ W2,
                     const float* __restrict__ Wres,
                     const uint4* __restrict__ sortedA, const u32* __restrict__ rankA,
                     int* __restrict__ knn1,
                     u16* __restrict__ ch0b, u16* __restrict__ W1b,
                     u16* __restrict__ W2b, u16* __restrict__ Wresb,
                     float* __restrict__ pos_out) {
    int blk = blockIdx.x, tid = threadIdx.x;
    int w = tid >> 6, lane = tid & 63;
    if (blk < 2048) {
        int wave = blk * 4 + w;                 // 8192 waves: 2 batches x 4096 centers
        int batch = wave >> 12, j = wave & 4095;
        const float* cp = pos0 + ((size_t)(batch * N0 + 2 * j)) * 3;
        float cx = cp[0], cy = cp[1], cz = cp[2];
        int r0 = (int)rankA[(size_t)batch * 8192 + 2 * j];
        u64 key = knn_sweep(sortedA + (size_t)batch * 8192, 8192, cx, cy, cz, r0, lane);
        if (lane < 16)
            knn1[((size_t)(batch * N1 + j)) * KNB + lane] = (int)(u32)key;
    } else if (blk < 2560) {          // ch0 -> bf16 (1,048,576 elems)
        cvt8(ch0, ch0b, ((blk - 2048) * 256 + tid) * 8);
    } else if (blk < 2624) {          // W1 -> bf16 (131,072)
        cvt8(W1, W1b, ((blk - 2560) * 256 + tid) * 8);
    } else if (blk < 2752) {          // W2 -> bf16 (262,144)
        cvt8(W2, W2b, ((blk - 2624) * 256 + tid) * 8);
    } else if (blk < 2784) {          // Wres[c][o] -> Wresb[o][c] bf16 (8192 elems)
        int t = (blk - 2752) * 256 + tid;
        int o = t >> 6, c = t & 63;
        Wresb[o * 64 + c] = f2bf(Wres[(size_t)c * COUT + o]);
    } else {                          // pos_out copy: 4096 rows (16 blocks)
        int t = (blk - 2784) * 256 + tid;
        int b = t >> 11, r = t & 2047;
        const float* s = pos0 + ((size_t)(b * N0 + r * 4)) * 3;
        float* d = pos_out + ((size_t)(b * N2 + r)) * 3;
        d[0] = s[0]; d[1] = s[1]; d[2] = s[2];
    }
}

// ---------------- dispatch 3: conv1 MFMA (512 blk) + knn2 sweep (1024 blk) ---------
__global__ __launch_bounds__(256)
void conv1_knn2_kernel(const u16* __restrict__ ch0b, const int* __restrict__ knn1,
                       const u16* __restrict__ W1b, const u16* __restrict__ Wresb,
                       const float* __restrict__ b1, const float* __restrict__ bres,
                       const float* __restrict__ g1, const float* __restrict__ be1,
                       u16* __restrict__ ch1b, u16* __restrict__ res1b,
                       const float* __restrict__ pos0,
                       const uint4* __restrict__ sortedB, const u32* __restrict__ rankB,
                       int* __restrict__ knn2) {
    __shared__ u16 As[16][72];        // 16 rows x 64 bf16, +8 pad
    __shared__ u16 Ws[128][72];       // 128 cols x 64 bf16, +8 pad
    __shared__ int knnr[16][16];
    __shared__ float red[16][4][2];
    __shared__ float cb[128], cg[128], cbe[128], cbr[128];

    int blk = blockIdx.x, tid = threadIdx.x;

    if (blk >= 512) {
        // knn2: 1 center/wave over level-1 sorted records (4096 candidates)
        int w = tid >> 6, lane = tid & 63;
        int wave = (blk - 512) * 4 + w;         // 4096 waves: 2 batches x 2048 centers
        int batch = wave >> 11, i = wave & 2047;
        const float* cp = pos0 + ((size_t)(batch * N0 + 4 * i)) * 3;
        float cx = cp[0], cy = cp[1], cz = cp[2];
        int r0 = (int)rankB[(size_t)batch * 4096 + 2 * i];
        u64 key = knn_sweep(sortedB + (size_t)batch * 4096, 4096, cx, cy, cz, r0, lane);
        if (lane < 16)
            knn2[((size_t)(batch * N2 + i)) * KNB + lane] = (int)(u32)key;
        return;
    }

    int cblk = blk;                   // 512 conv1 blocks
    int b = cblk >> 8, g = cblk & 255;
    int jbase = g * 16;

    if (tid < 128) { cb[tid] = b1[tid]; cg[tid] = g1[tid]; cbe[tid] = be1[tid]; cbr[tid] = bres[tid]; }
    {   // 256 knn ints, 1 per thread
        int r = tid >> 4, k = tid & 15;
        knnr[r][k] = knn1[((size_t)(b * N1 + jbase + r)) * KNB + k];
    }
    __syncthreads();

    int w = tid >> 6, lane = tid & 63, quad = lane >> 4, l15 = lane & 15;
    int wcol = w * 32;
    int ar = tid >> 4, ap = tid & 15;     // A staging: 16 rows x 16 chunks of 8B
    int wn = tid >> 1, wh = tid & 1;      // W staging: 128 cols x 2 halves of 64B

    f32x4 acc[2] = {{0,0,0,0},{0,0,0,0}};
    f32x4 racc[2] = {{0,0,0,0},{0,0,0,0}};

    // software pipeline: prefetch chunk 0
    uint2 aR = *((const uint2*)(ch0b + ((size_t)(b * N0 + knnr[ar][0])) * 64) + ap);
    uint4 wR[4];
    {
        const uint4* s4 = (const uint4*)(W1b + (size_t)wn * 1024 + wh * 32);
        wR[0] = s4[0]; wR[1] = s4[1]; wR[2] = s4[2]; wR[3] = s4[3];
    }
    for (int kn = 0; kn < 17; ++kn) {     // 16 neighbor chunks + 1 residual chunk
        *(uint2*)&As[ar][ap * 4] = aR;
        uint4* d4 = (uint4*)&Ws[wn][wh * 32];
        d4[0] = wR[0]; d4[1] = wR[1]; d4[2] = wR[2]; d4[3] = wR[3];
        __syncthreads();
        if (kn < 16) {  // prefetch next chunk (kn==15 -> residual sources)
            int nidx = (kn < 15) ? knnr[ar][kn + 1] : 2 * (jbase + ar);
            aR = *((const uint2*)(ch0b + ((size_t)(b * N0 + nidx)) * 64) + ap);
            const uint4* s4 = (kn < 15)
                ? (const uint4*)(W1b + (size_t)wn * 1024 + (kn + 1) * 64 + wh * 32)
                : (const uint4*)(Wresb + (size_t)wn * 64 + wh * 32);
            wR[0] = s4[0]; wR[1] = s4[1]; wR[2] = s4[2]; wR[3] = s4[3];
        }
        if (kn < 16) {
#pragma unroll
            for (int ks = 0; ks < 2; ++ks) {
                bf16x8 af = *(const bf16x8*)&As[l15][ks * 32 + quad * 8];
#pragma unroll
                for (int nt = 0; nt < 2; ++nt) {
                    bf16x8 bfr = *(const bf16x8*)&Ws[wcol + nt * 16 + l15][ks * 32 + quad * 8];
                    acc[nt] = __builtin_amdgcn_mfma_f32_16x16x32_bf16(af, bfr, acc[nt], 0, 0, 0);
                }
            }
        } else {
#pragma unroll
            for (int ks = 0; ks < 2; ++ks) {
                bf16x8 af = *(const bf16x8*)&As[l15][ks * 32 + quad * 8];
#pragma unroll
                for (int nt = 0; nt < 2; ++nt) {
                    bf16x8 bfr = *(const bf16x8*)&Ws[wcol + nt * 16 + l15][ks * 32 + quad * 8];
                    racc[nt] = __builtin_amdgcn_mfma_f32_16x16x32_bf16(af, bfr, racc[nt], 0, 0, 0);
                }
            }
        }
        __syncthreads();
    }

    // epilogue: bias + LN(+SiLU) on conv acc; bias on residual; both stored bf16
    float x[2][4], s[4] = {0,0,0,0}, ss[4] = {0,0,0,0};
#pragma unroll
    for (int reg = 0; reg < 4; ++reg)
#pragma unroll
        for (int nt = 0; nt < 2; ++nt) {
            int col = wcol + nt * 16 + l15;
            float v = acc[nt][reg] + cb[col];
            x[nt][reg] = v;
            s[reg] += v; ss[reg] += v * v;
        }
#pragma unroll
    for (int m = 1; m < 16; m <<= 1)
#pragma unroll
        for (int reg = 0; reg < 4; ++reg) {
            s[reg] += __shfl_xor(s[reg], m, 64);
            ss[reg] += __shfl_xor(ss[reg], m, 64);
        }
    if (l15 == 0) {
#pragma unroll
        for (int reg = 0; reg < 4; ++reg) {
            red[quad * 4 + reg][w][0] = s[reg];
            red[quad * 4 + reg][w][1] = ss[reg];
        }
    }
    __syncthreads();
    float mu[4], rs[4];
#pragma unroll
    for (int reg = 0; reg < 4; ++reg) {
        int row = quad * 4 + reg;
        float S = red[row][0][0] + red[row][1][0] + red[row][2][0] + red[row][3][0];
        float SS = red[row][0][1] + red[row][1][1] + red[row][2][1] + red[row][3][1];
        mu[reg] = S * (1.f / 128.f);
        float var = fmaxf(SS * (1.f / 128.f) - mu[reg] * mu[reg], 0.f);
        rs[reg] = 1.f / sqrtf(var + 1e-5f);
    }
#pragma unroll
    for (int nt = 0; nt < 2; ++nt)
#pragma unroll
        for (int reg = 0; reg < 4; ++reg) {
            int col = wcol + nt * 16 + l15;
            int row = quad * 4 + reg;
            size_t off = ((size_t)(b * N1 + jbase + row)) * COUT + col;
            float y = (x[nt][reg] - mu[reg]) * rs[reg] * cg[col] + cbe[col];
            ch1b[off] = f2bf(y / (1.f + __expf(-y)));
            res1b[off] = f2bf(racc[nt][reg] + cbr[col]);
        }
}

// ---------------- dispatch 4: conv2 MFMA K=2048, 512 threads (8 waves), M=16 -------
__global__ __launch_bounds__(512)
void conv2_kernel(const u16* __restrict__ ch1b, const int* __restrict__ knn2,
                  const u16* __restrict__ W2b, const float* __restrict__ b2,
                  const float* __restrict__ g2, const float* __restrict__ be2,
                  const u16* __restrict__ res1b, float* __restrict__ ch_out) {
    __shared__ u16 As[16][136];       // 16 rows x 128 bf16, +8 pad
    __shared__ u16 Ws[128][136];
    __shared__ int knnr[16][16];
    __shared__ float red[16][8][2];
    __shared__ float cb[128], cg[128], cbe[128];

    int tid = threadIdx.x;            // 0..511
    int b = blockIdx.x >> 7, g = blockIdx.x & 127;
    int ibase = g * 16;

    if (tid < 128) { cb[tid] = b2[tid]; cg[tid] = g2[tid]; cbe[tid] = be2[tid]; }
    if (tid < 256) {
        int r = tid >> 4, k = tid & 15;
        knnr[r][k] = knn2[((size_t)(b * N2 + ibase + r)) * KNB + k];
    }
    __syncthreads();

    int w = tid >> 6, lane = tid & 63, quad = lane >> 4, l15 = lane & 15;
    int wcol = w * 16;
    int ar = tid >> 5, ap = tid & 31;     // A staging: 16 rows x 32 chunks of 8B
    int wn = tid >> 2, wq = tid & 3;      // W staging: 128 cols x 4 chunks of 64B

    f32x4 acc = {0, 0, 0, 0};

    uint2 aR = *((const uint2*)(ch1b + ((size_t)(b * N1 + knnr[ar][0])) * COUT) + ap);
    uint4 wR[4];
    {
        const uint4* s4 = (const uint4*)(W2b + (size_t)wn * 2048 + wq * 32);
        wR[0] = s4[0]; wR[1] = s4[1]; wR[2] = s4[2]; wR[3] = s4[3];
    }
    for (int kn = 0; kn < 16; ++kn) {
        *(uint2*)&As[ar][ap * 4] = aR;
        uint4* d4 = (uint4*)&Ws[wn][wq * 32];
        d4[0] = wR[0]; d4[1] = wR[1]; d4[2] = wR[2]; d4[3] = wR[3];
        __syncthreads();
        if (kn < 15) {
            aR = *((const uint2*)(ch1b + ((size_t)(b * N1 + knnr[ar][kn + 1])) * COUT) + ap);
            const uint4* s4 = (const uint4*)(W2b + (size_t)wn * 2048 + (kn + 1) * 128 + wq * 32);
            wR[0] = s4[0]; wR[1] = s4[1]; wR[2] = s4[2]; wR[3] = s4[3];
        }
#pragma unroll
        for (int ks = 0; ks < 4; ++ks) {
            bf16x8 af = *(const bf16x8*)&As[l15][ks * 32 + quad * 8];
            bf16x8 bfr = *(const bf16x8*)&Ws[wcol + l15][ks * 32 + quad * 8];
            acc = __builtin_amdgcn_mfma_f32_16x16x32_bf16(af, bfr, acc, 0, 0, 0);
        }
        __syncthreads();
    }

    float x[4], s[4], ss[4];
#pragma unroll
    for (int reg = 0; reg < 4; ++reg) {
        int col = wcol + l15;
        float v = acc[reg] + cb[col];
        x[reg] = v; s[reg] = v; ss[reg] = v * v;
    }
#pragma unroll
    for (int m = 1; m < 16; m <<= 1)
#pragma unroll
        for (int reg = 0; reg < 4; ++reg) {
            s[reg] += __shfl_xor(s[reg], m, 64);
            ss[reg] += __shfl_xor(ss[reg], m, 64);
        }
    if (l15 == 0) {
#pragma unroll
        for (int reg = 0; reg < 4; ++reg) {
            red[quad * 4 + reg][w][0] = s[reg];
            red[quad * 4 + reg][w][1] = ss[reg];
        }
    }
    __syncthreads();
#pragma unroll
    for (int reg = 0; reg < 4; ++reg) {
        int row = quad * 4 + reg;
        float S = 0.f, SS = 0.f;
#pragma unroll
        for (int t = 0; t < 8; ++t) { S += red[row][t][0]; SS += red[row][t][1]; }
        float mu = S * (1.f / 128.f);
        float var = fmaxf(SS * (1.f / 128.f) - mu * mu, 0.f);
        float rs = 1.f / sqrtf(var + 1e-5f);
        int col = wcol + l15;
        int i = ibase + row;
        float y = (x[reg] - mu) * rs * cg[col] + cbe[col];
        float sl = y / (1.f + __expf(-y));
        float rv = bf2f(res1b[((size_t)(b * N1 + 2 * i)) * COUT + col]);
        ch_out[((size_t)(b * N2 + i)) * COUT + col] = sl + rv;
    }
}

extern "C" void kernel_launch(void* const* d_in, const int* in_sizes, int n_in,
                              void* d_out, int out_size, void* d_ws, size_t ws_size,
                              hipStream_t stream) {
    const float* pos0 = (const float*)d_in[0];
    const float* ch0  = (const float*)d_in[1];
    const float* W1   = (const float*)d_in[2];
    const float* b1   = (const float*)d_in[3];
    const float* Wres = (const float*)d_in[4];
    const float* bres = (const float*)d_in[5];
    const float* W2   = (const float*)d_in[6];
    const float* b2   = (const float*)d_in[7];
    const float* g1   = (const float*)d_in[8];
    const float* be1  = (const float*)d_in[9];
    const float* g2   = (const float*)d_in[10];
    const float* be2  = (const float*)d_in[11];
    float* out = (float*)d_out;

    char* ws = (char*)d_ws;
    int*  knn1  = (int*)(ws);                      // 524288
    int*  knn2  = (int*)(ws + 524288);             // 262144
    u16*  ch0b  = (u16*)(ws + 786432);             // 2097152
    u16*  W1b   = (u16*)(ws + 2883584);            // 262144
    u16*  W2b   = (u16*)(ws + 3145728);            // 524288
    u16*  Wresb = (u16*)(ws + 3670016);            // 16384
    u16*  ch1b  = (u16*)(ws + 3686400);            // 2097152
    u16*  res1b = (u16*)(ws + 5783552);            // 2097152
    uint4* sortedA = (uint4*)(ws + 7880704);       // 262144 (2 x 8192 x 16B)
    uint4* sortedB = (uint4*)(ws + 8142848);       // 131072 (2 x 4096 x 16B)
    u32*  rankA = (u32*)(ws + 8273920);            // 65536
    u32*  rankB = (u32*)(ws + 8339456);            // 32768  (total ~8.0 MB)

    float* pos_out = out;          // [2,2048,3] fp32
    float* ch_out  = out + 12288;  // [2,2048,128] fp32

    sort_kernel<<<4, 256, 0, stream>>>(pos0, sortedA, rankA, sortedB, rankB);
    knn_prep_kernel<<<2800, 256, 0, stream>>>(pos0, ch0, W1, W2, Wres,
                                              sortedA, rankA, knn1,
                                              ch0b, W1b, W2b, Wresb, pos_out);
    conv1_knn2_kernel<<<1536, 256, 0, stream>>>(ch0b, knn1, W1b, Wresb, b1, bres, g1, be1,
                                                ch1b, res1b, pos0, sortedB, rankB, knn2);
    conv2_kernel<<<256, 512, 0, stream>>>(ch1b, knn2, W2b, b2, g2, be2, res1b, ch_out);
}

// Round 3
// 226.582 us; speedup vs baseline: 1.1105x; 1.1105x over previous
//
#include <hip/hip_runtime.h>
#include <cstdint>
#include <cstddef>

using u16 = unsigned short;
using u32 = unsigned int;
using u64 = unsigned long long;

typedef short bf16x8 __attribute__((ext_vector_type(8)));
typedef float f32x4 __attribute__((ext_vector_type(4)));

constexpr int N0 = 8192;
constexpr int N1 = 4096;
constexpr int N2 = 2048;
constexpr int COUT = 128;
constexpr int KNB = 16;

// x-bucket sort parameters: monotone u32 key, top 13 bits = bucket (sign+exp+4 mantissa)
constexpr int BSHIFT = 19;
constexpr int NBUCK = 8192;               // 2^(32-19)
constexpr u32 BMASK = 0xFFF80000u;        // bucket floor mask
constexpr u32 BINC  = 0x00080000u;        // one bucket

__device__ __forceinline__ float bf2f(u16 v) { return __uint_as_float(((u32)v) << 16); }
__device__ __forceinline__ u16 f2bf(float f) {  // round-to-nearest-even
    u32 u = __float_as_uint(f);
    return (u16)((u + 0x7fffu + ((u >> 16) & 1u)) >> 16);
}
__device__ __forceinline__ void cvt8(const float* __restrict__ src, u16* __restrict__ dst, int e) {
    float t0[8];
    *(float4*)t0 = *(const float4*)(src + e);
    *(float4*)(t0 + 4) = *(const float4*)(src + e + 4);
    u16 o[8];
#pragma unroll
    for (int q = 0; q < 8; ++q) o[q] = f2bf(t0[q]);
    *(uint4*)(dst + e) = *(uint4*)o;
}

// Distances must match the np reference bit-exactly: no FMA contraction, sequential sum.
__device__ __forceinline__ float dist2s(float cx, float cy, float cz,
                                        float px, float py, float pz) {
#pragma clang fp contract(off)
    float dx = cx - px;
    float dy = cy - py;
    float dz = cz - pz;
    float s = dx * dx;
    s = s + dy * dy;
    s = s + dz * dz;
    return s;
}

// monotone u32 of float bits (strictly increasing in float order, non-NaN)
__device__ __forceinline__ u32 monot(u32 u) {
    return (u & 0x80000000u) ? ~u : (u | 0x80000000u);
}
// inverse of monotone transform (valid for any bucket-boundary key)
__device__ __forceinline__ float invmono(u32 k) {
    return (k & 0x80000000u) ? __uint_as_float(k & 0x7FFFFFFFu) : __uint_as_float(~k);
}

// ---- DPP cross-lane helpers (VALU pipe, no LDS traffic) ----
template <int CTRL>
__device__ __forceinline__ u64 dpp64(u64 v) {
    int lo = (int)(u32)v, hi = (int)(u32)(v >> 32);
    int plo = __builtin_amdgcn_update_dpp(0, lo, CTRL, 0xF, 0xF, true);
    int phi = __builtin_amdgcn_update_dpp(0, hi, CTRL, 0xF, 0xF, true);
    return (((u64)(u32)phi) << 32) | (u32)plo;
}
// row_shr:1 with bound_ctrl=1: lane L gets lane L-1; lane 0 of each 16-row gets 0.
__device__ __forceinline__ u64 dpp_prev_u64(u64 v) { return dpp64<0x111>(v); }

__device__ __forceinline__ u32 rdlane(u32 v, int l) {
    return (u32)__builtin_amdgcn_readlane((int)v, l);
}

// ---------------- dispatch 1: sort (4 blk) + bf16 prep copies, 1024 threads -------
// Records: uint4 {bits(x), bits(y), bits(z), orig_idx}. rank[orig] = sorted slot.
// Within-bucket order arbitrary (atomic scatter) — pruning uses bucket boundaries only,
// and the top-16 key set is insertion-order independent, so output stays exact.
__global__ __launch_bounds__(1024)
void sort_prep_kernel(const float* __restrict__ pos0, const float* __restrict__ ch0,
                      const float* __restrict__ W1, const float* __restrict__ W2,
                      const float* __restrict__ Wres,
                      uint4* __restrict__ sortedA, u32* __restrict__ rankA,
                      uint4* __restrict__ sortedB, u32* __restrict__ rankB,
                      u16* __restrict__ ch0b, u16* __restrict__ W1b,
                      u16* __restrict__ W2b, u16* __restrict__ Wresb,
                      float* __restrict__ pos_out) {
    __shared__ u32 hist[NBUCK];
    __shared__ u32 tot[1024];
    int blk = blockIdx.x, tid = threadIdx.x;
    if (blk < 4) {
        int b = blk >> 1, lvl = blk & 1;
        int n = lvl ? 4096 : 8192;
        int pst = lvl ? 6 : 3;
        const float* P = pos0 + (size_t)b * N0 * 3;
        uint4* recs = lvl ? (sortedB + (size_t)b * 4096) : (sortedA + (size_t)b * 8192);
        u32* rank = lvl ? (rankB + (size_t)b * 4096) : (rankA + (size_t)b * 8192);

        for (int i = tid; i < NBUCK; i += 1024) hist[i] = 0;
        __syncthreads();
        for (int i = tid; i < n; i += 1024) {
            u32 key = monot(__float_as_uint(P[(size_t)i * pst]));
            atomicAdd(&hist[key >> BSHIFT], 1u);
        }
        __syncthreads();
        // exclusive scan of hist: 8 slots/thread in registers, then block scan
        u32 vals[8];
        int base = tid * 8;
        *(uint4*)&vals[0] = *(uint4*)&hist[base];
        *(uint4*)&vals[4] = *(uint4*)&hist[base + 4];
        u32 run = 0;
#pragma unroll
        for (int j = 0; j < 8; ++j) { u32 c = vals[j]; vals[j] = run; run += c; }
        tot[tid] = run;
        __syncthreads();
        for (int off = 1; off < 1024; off <<= 1) {
            u32 v = (tid >= off) ? tot[tid - off] : 0;
            __syncthreads();
            tot[tid] += v;
            __syncthreads();
        }
        u32 add = (tid > 0) ? tot[tid - 1] : 0;
#pragma unroll
        for (int j = 0; j < 8; ++j) vals[j] += add;
        *(uint4*)&hist[base] = *(uint4*)&vals[0];
        *(uint4*)&hist[base + 4] = *(uint4*)&vals[4];
        __syncthreads();
        // scatter (hist now = running cursor per bucket)
        for (int i = tid; i < n; i += 1024) {
            const float* pp = P + (size_t)i * pst;
            float x = pp[0], y = pp[1], z = pp[2];
            u32 key = monot(__float_as_uint(x));
            u32 slot = atomicAdd(&hist[key >> BSHIFT], 1u);
            uint4 r;
            r.x = __float_as_uint(x); r.y = __float_as_uint(y); r.z = __float_as_uint(z);
            r.w = (u32)i;
            recs[slot] = r;
            rank[i] = slot;
        }
    } else if (blk < 132) {           // ch0 -> bf16 (1,048,576 elems)
        cvt8(ch0, ch0b, ((blk - 4) * 1024 + tid) * 8);
    } else if (blk < 148) {           // W1 -> bf16 (131,072)
        cvt8(W1, W1b, ((blk - 132) * 1024 + tid) * 8);
    } else if (blk < 180) {           // W2 -> bf16 (262,144)
        cvt8(W2, W2b, ((blk - 148) * 1024 + tid) * 8);
    } else if (blk < 188) {           // Wres[c][o] -> Wresb[o][c] bf16 (8192 elems)
        int t = (blk - 180) * 1024 + tid;
        int o = t >> 6, c = t & 63;
        Wresb[o * 64 + c] = f2bf(Wres[(size_t)c * COUT + o]);
    } else {                          // pos_out copy: 4096 rows (4 blocks)
        int t = (blk - 188) * 1024 + tid;
        int b = t >> 11, r = t & 2047;
        const float* s = pos0 + ((size_t)(b * N0 + r * 4)) * 3;
        float* d = pos_out + ((size_t)(b * N2 + r)) * 3;
        d[0] = s[0]; d[1] = s[1]; d[2] = s[2];
    }
}

// ---------------- exact pruned+PIPELINED KNN sweep over x-sorted records -----------
// Chunk = 128 records/side-step (2 loads), depth-2 prefetch per side; side loads issued
// before the bitonic warm start so its ~500cy hide them. Prune bounds & insert machinery
// identical to the proven version (bucket floor/ceil, superset u32 filter, exact u64 cmp).
__device__ __forceinline__ u64 knn_sweep(const uint4* __restrict__ recs, int n,
                                         float cx, float cy, float cz,
                                         int r0, int lane) {
    int wb = r0 - 32;
    if (wb < 0) wb = 0;
    if (wb > n - 64) wb = n - 64;

    uint4 wrec = recs[wb + lane];     // warm-start chunk

    int R = wb + 64;                  // right chunk base: [R, R+128)
    int L = wb - 128;                 // left  chunk base: [L, L+128)
    bool rA = (R < n), lA = (L > -128);
    uint4 ra0, ra1, rb0, rb1, la0, la1, lb0, lb1;
    if (rA) {                         // current + one-ahead (issued before bitonic)
        ra0 = recs[min(R + lane, n - 1)];
        ra1 = recs[min(R + 64 + lane, n - 1)];
        rb0 = recs[min(R + 128 + lane, n - 1)];
        rb1 = recs[min(R + 192 + lane, n - 1)];
    }
    if (lA) {
        la0 = recs[max(L + lane, 0)];
        la1 = recs[max(L + 64 + lane, 0)];
        lb0 = recs[max(L - 128 + lane, 0)];
        lb1 = recs[max(L - 64 + lane, 0)];
    }

    u64 key;
    {   // warm start: bitonic-sort the 64 records around the center's rank
        float px = __uint_as_float(wrec.x), py = __uint_as_float(wrec.y), pz = __uint_as_float(wrec.z);
        u64 k = (((u64)__float_as_uint(dist2s(cx, cy, cz, px, py, pz))) << 32) | wrec.w;
#pragma unroll
        for (int kk = 2; kk <= 64; kk <<= 1)
#pragma unroll
            for (int jj = kk >> 1; jj > 0; jj >>= 1) {
                u64 o;
                if (jj == 1)      o = dpp64<0xB1>(k);
                else if (jj == 2) o = dpp64<0x4E>(k);
                else if (jj == 8) o = dpp64<0x128>(k);
                else              o = __shfl_xor(k, jj, 64);
                bool keepmin = (((lane & jj) == 0) == ((lane & kk) == 0));
                k = keepmin ? ((o < k) ? o : k) : ((o > k) ? o : k);
            }
        key = k;
    }
    u32 cut = rdlane((u32)(key >> 32), 15);
    float cutf = __uint_as_float(cut);

    while (rA || lA) {
        if (rA) {
            // remaining-right x >= bucket floor of record R (lane 0 of ra0)
            u32 kb = monot(rdlane(ra0.x, 0)) & BMASK;
            float fdx = invmono(kb) - cx;
            if (fdx > 0.f && fdx * fdx > cutf) {
                rA = false;
            } else {
                u32 d0 = (R + lane < n)
                    ? __float_as_uint(dist2s(cx, cy, cz, __uint_as_float(ra0.x),
                                             __uint_as_float(ra0.y), __uint_as_float(ra0.z)))
                    : 0xFFFFFFFFu;
                u32 d1 = (R + 64 + lane < n)
                    ? __float_as_uint(dist2s(cx, cy, cz, __uint_as_float(ra1.x),
                                             __uint_as_float(ra1.y), __uint_as_float(ra1.z)))
                    : 0xFFFFFFFFu;
                u32 i0 = ra0.w, i1 = ra1.w;
                u64 b0 = __ballot(d0 <= cut);
                u64 b1 = __ballot(d1 <= cut);
                bool any = (b0 | b1) != 0;
                while (b0 | b1) {
                    if (b0) {
                        int src = __ffsll((unsigned long long)b0) - 1;
                        b0 &= b0 - 1;
                        u64 nk = (((u64)rdlane(d0, src)) << 32) | rdlane(i0, src);
                        u64 prev = dpp_prev_u64(key);
                        key = (nk < key) ? ((nk < prev) ? prev : nk) : key;
                    }
                    if (b1) {
                        int src = __ffsll((unsigned long long)b1) - 1;
                        b1 &= b1 - 1;
                        u64 nk = (((u64)rdlane(d1, src)) << 32) | rdlane(i1, src);
                        u64 prev = dpp_prev_u64(key);
                        key = (nk < key) ? ((nk < prev) ? prev : nk) : key;
                    }
                }
                if (any) { cut = rdlane((u32)(key >> 32), 15); cutf = __uint_as_float(cut); }
                R += 128;
                rA = (R < n);
                if (rA) {             // rotate pipeline, issue next-ahead chunk
                    ra0 = rb0; ra1 = rb1;
                    rb0 = recs[min(R + 128 + lane, n - 1)];
                    rb1 = recs[min(R + 192 + lane, n - 1)];
                }
            }
        }
        if (lA) {
            // remaining-left x < bucket ceil of record L+127 (lane 63 of la1)
            u32 kb = monot(rdlane(la1.x, 63)) & BMASK;
            bool prune = false;
            if (kb != BMASK) {  // top bucket: can't form ceil, skip prune
                float gdx = cx - invmono(kb + BINC);
                prune = (gdx > 0.f && gdx * gdx > cutf);
            }
            if (prune) {
                lA = false;
            } else {
                u32 d0 = (L + lane >= 0)
                    ? __float_as_uint(dist2s(cx, cy, cz, __uint_as_float(la0.x),
                                             __uint_as_float(la0.y), __uint_as_float(la0.z)))
                    : 0xFFFFFFFFu;
                u32 d1 = (L + 64 + lane >= 0)
                    ? __float_as_uint(dist2s(cx, cy, cz, __uint_as_float(la1.x),
                                             __uint_as_float(la1.y), __uint_as_float(la1.z)))
                    : 0xFFFFFFFFu;
                u32 i0 = la0.w, i1 = la1.w;
                u64 b0 = __ballot(d0 <= cut);
                u64 b1 = __ballot(d1 <= cut);
                bool any = (b0 | b1) != 0;
                while (b0 | b1) {
                    if (b0) {
                        int src = __ffsll((unsigned long long)b0) - 1;
                        b0 &= b0 - 1;
                        u64 nk = (((u64)rdlane(d0, src)) << 32) | rdlane(i0, src);
                        u64 prev = dpp_prev_u64(key);
                        key = (nk < key) ? ((nk < prev) ? prev : nk) : key;
                    }
                    if (b1) {
                        int src = __ffsll((unsigned long long)b1) - 1;
                        b1 &= b1 - 1;
                        u64 nk = (((u64)rdlane(d1, src)) << 32) | rdlane(i1, src);
                        u64 prev = dpp_prev_u64(key);
                        key = (nk < key) ? ((nk < prev) ? prev : nk) : key;
                    }
                }
                if (any) { cut = rdlane((u32)(key >> 32), 15); cutf = __uint_as_float(cut); }
                L -= 128;
                lA = (L > -128);
                if (lA) {
                    la0 = lb0; la1 = lb1;
                    lb0 = recs[max(L - 128 + lane, 0)];
                    lb1 = recs[max(L - 64 + lane, 0)];
                }
            }
        }
    }
    return key;
}

// ---------------- dispatch 2: knn1 only (2048 blk, 1 center/wave) ------------------
__global__ __launch_bounds__(256)
void knn_prep_kernel(const float* __restrict__ pos0,
                     const uint4* __restrict__ sortedA, const u32* __restrict__ rankA,
                     int* __restrict__ knn1) {
    int blk = blockIdx.x, tid = threadIdx.x;
    int w = tid >> 6, lane = tid & 63;
    int wave = blk * 4 + w;                 // 8192 waves: 2 batches x 4096 centers
    int batch = wave >> 12, j = wave & 4095;
    const float* cp = pos0 + ((size_t)(batch * N0 + 2 * j)) * 3;
    float cx = cp[0], cy = cp[1], cz = cp[2];
    int r0 = (int)rankA[(size_t)batch * 8192 + 2 * j];
    u64 key = knn_sweep(sortedA + (size_t)batch * 8192, 8192, cx, cy, cz, r0, lane);
    if (lane < 16)
        knn1[((size_t)(batch * N1 + j)) * KNB + lane] = (int)(u32)key;
}

// ---------------- dispatch 3: conv1 MFMA (512 blk) + knn2 sweep (1024 blk) ---------
__global__ __launch_bounds__(256)
void conv1_knn2_kernel(const u16* __restrict__ ch0b, const int* __restrict__ knn1,
                       const u16* __restrict__ W1b, const u16* __restrict__ Wresb,
                       const float* __restrict__ b1, const float* __restrict__ bres,
                       const float* __restrict__ g1, const float* __restrict__ be1,
                       u16* __restrict__ ch1b, u16* __restrict__ res1b,
                       const float* __restrict__ pos0,
                       const uint4* __restrict__ sortedB, const u32* __restrict__ rankB,
                       int* __restrict__ knn2) {
    __shared__ u16 As[16][72];        // 16 rows x 64 bf16, +8 pad
    __shared__ u16 Ws[128][72];       // 128 cols x 64 bf16, +8 pad
    __shared__ int knnr[16][16];
    __shared__ float red[16][4][2];
    __shared__ float cb[128], cg[128], cbe[128], cbr[128];

    int blk = blockIdx.x, tid = threadIdx.x;

    if (blk >= 512) {
        // knn2: 1 center/wave over level-1 sorted records (4096 candidates)
        int w = tid >> 6, lane = tid & 63;
        int wave = (blk - 512) * 4 + w;         // 4096 waves: 2 batches x 2048 centers
        int batch = wave >> 11, i = wave & 2047;
        const float* cp = pos0 + ((size_t)(batch * N0 + 4 * i)) * 3;
        float cx = cp[0], cy = cp[1], cz = cp[2];
        int r0 = (int)rankB[(size_t)batch * 4096 + 2 * i];
        u64 key = knn_sweep(sortedB + (size_t)batch * 4096, 4096, cx, cy, cz, r0, lane);
        if (lane < 16)
            knn2[((size_t)(batch * N2 + i)) * KNB + lane] = (int)(u32)key;
        return;
    }

    int cblk = blk;                   // 512 conv1 blocks
    int b = cblk >> 8, g = cblk & 255;
    int jbase = g * 16;

    if (tid < 128) { cb[tid] = b1[tid]; cg[tid] = g1[tid]; cbe[tid] = be1[tid]; cbr[tid] = bres[tid]; }
    {   // 256 knn ints, 1 per thread
        int r = tid >> 4, k = tid & 15;
        knnr[r][k] = knn1[((size_t)(b * N1 + jbase + r)) * KNB + k];
    }
    __syncthreads();

    int w = tid >> 6, lane = tid & 63, quad = lane >> 4, l15 = lane & 15;
    int wcol = w * 32;
    int ar = tid >> 4, ap = tid & 15;     // A staging: 16 rows x 16 chunks of 8B
    int wn = tid >> 1, wh = tid & 1;      // W staging: 128 cols x 2 halves of 64B

    f32x4 acc[2] = {{0,0,0,0},{0,0,0,0}};
    f32x4 racc[2] = {{0,0,0,0},{0,0,0,0}};

    // software pipeline: prefetch chunk 0
    uint2 aR = *((const uint2*)(ch0b + ((size_t)(b * N0 + knnr[ar][0])) * 64) + ap);
    uint4 wR[4];
    {
        const uint4* s4 = (const uint4*)(W1b + (size_t)wn * 1024 + wh * 32);
        wR[0] = s4[0]; wR[1] = s4[1]; wR[2] = s4[2]; wR[3] = s4[3];
    }
    for (int kn = 0; kn < 17; ++kn) {     // 16 neighbor chunks + 1 residual chunk
        *(uint2*)&As[ar][ap * 4] = aR;
        uint4* d4 = (uint4*)&Ws[wn][wh * 32];
        d4[0] = wR[0]; d4[1] = wR[1]; d4[2] = wR[2]; d4[3] = wR[3];
        __syncthreads();
        if (kn < 16) {  // prefetch next chunk (kn==15 -> residual sources)
            int nidx = (kn < 15) ? knnr[ar][kn + 1] : 2 * (jbase + ar);
            aR = *((const uint2*)(ch0b + ((size_t)(b * N0 + nidx)) * 64) + ap);
            const uint4* s4 = (kn < 15)
                ? (const uint4*)(W1b + (size_t)wn * 1024 + (kn + 1) * 64 + wh * 32)
                : (const uint4*)(Wresb + (size_t)wn * 64 + wh * 32);
            wR[0] = s4[0]; wR[1] = s4[1]; wR[2] = s4[2]; wR[3] = s4[3];
        }
        if (kn < 16) {
#pragma unroll
            for (int ks = 0; ks < 2; ++ks) {
                bf16x8 af = *(const bf16x8*)&As[l15][ks * 32 + quad * 8];
#pragma unroll
                for (int nt = 0; nt < 2; ++nt) {
                    bf16x8 bfr = *(const bf16x8*)&Ws[wcol + nt * 16 + l15][ks * 32 + quad * 8];
                    acc[nt] = __builtin_amdgcn_mfma_f32_16x16x32_bf16(af, bfr, acc[nt], 0, 0, 0);
                }
            }
        } else {
#pragma unroll
            for (int ks = 0; ks < 2; ++ks) {
                bf16x8 af = *(const bf16x8*)&As[l15][ks * 32 + quad * 8];
#pragma unroll
                for (int nt = 0; nt < 2; ++nt) {
                    bf16x8 bfr = *(const bf16x8*)&Ws[wcol + nt * 16 + l15][ks * 32 + quad * 8];
                    racc[nt] = __builtin_amdgcn_mfma_f32_16x16x32_bf16(af, bfr, racc[nt], 0, 0, 0);
                }
            }
        }
        __syncthreads();
    }

    // epilogue: bias + LN(+SiLU) on conv acc; bias on residual; both stored bf16
    float x[2][4], s[4] = {0,0,0,0}, ss[4] = {0,0,0,0};
#pragma unroll
    for (int reg = 0; reg < 4; ++reg)
#pragma unroll
        for (int nt = 0; nt < 2; ++nt) {
            int col = wcol + nt * 16 + l15;
            float v = acc[nt][reg] + cb[col];
            x[nt][reg] = v;
            s[reg] += v; ss[reg] += v * v;
        }
#pragma unroll
    for (int m = 1; m < 16; m <<= 1)
#pragma unroll
        for (int reg = 0; reg < 4; ++reg) {
            s[reg] += __shfl_xor(s[reg], m, 64);
            ss[reg] += __shfl_xor(ss[reg], m, 64);
        }
    if (l15 == 0) {
#pragma unroll
        for (int reg = 0; reg < 4; ++reg) {
            red[quad * 4 + reg][w][0] = s[reg];
            red[quad * 4 + reg][w][1] = ss[reg];
        }
    }
    __syncthreads();
    float mu[4], rs[4];
#pragma unroll
    for (int reg = 0; reg < 4; ++reg) {
        int row = quad * 4 + reg;
        float S = red[row][0][0] + red[row][1][0] + red[row][2][0] + red[row][3][0];
        float SS = red[row][0][1] + red[row][1][1] + red[row][2][1] + red[row][3][1];
        mu[reg] = S * (1.f / 128.f);
        float var = fmaxf(SS * (1.f / 128.f) - mu[reg] * mu[reg], 0.f);
        rs[reg] = 1.f / sqrtf(var + 1e-5f);
    }
#pragma unroll
    for (int nt = 0; nt < 2; ++nt)
#pragma unroll
        for (int reg = 0; reg < 4; ++reg) {
            int col = wcol + nt * 16 + l15;
            int row = quad * 4 + reg;
            size_t off = ((size_t)(b * N1 + jbase + row)) * COUT + col;
            float y = (x[nt][reg] - mu[reg]) * rs[reg] * cg[col] + cbe[col];
            ch1b[off] = f2bf(y / (1.f + __expf(-y)));
            res1b[off] = f2bf(racc[nt][reg] + cbr[col]);
        }
}

// ---------------- dispatch 4: conv2 MFMA K=2048, 512 threads (8 waves), M=16 -------
__global__ __launch_bounds__(512)
void conv2_kernel(const u16* __restrict__ ch1b, const int* __restrict__ knn2,
                  const u16* __restrict__ W2b, const float* __restrict__ b2,
                  const float* __restrict__ g2, const float* __restrict__ be2,
                  const u16* __restrict__ res1b, float* __restrict__ ch_out) {
    __shared__ u16 As[16][136];       // 16 rows x 128 bf16, +8 pad
    __shared__ u16 Ws[128][136];
    __shared__ int knnr[16][16];
    __shared__ float red[16][8][2];
    __shared__ float cb[128], cg[128], cbe[128];

    int tid = threadIdx.x;            // 0..511
    int b = blockIdx.x >> 7, g = blockIdx.x & 127;
    int ibase = g * 16;

    if (tid < 128) { cb[tid] = b2[tid]; cg[tid] = g2[tid]; cbe[tid] = be2[tid]; }
    if (tid < 256) {
        int r = tid >> 4, k = tid & 15;
        knnr[r][k] = knn2[((size_t)(b * N2 + ibase + r)) * KNB + k];
    }
    __syncthreads();

    int w = tid >> 6, lane = tid & 63, quad = lane >> 4, l15 = lane & 15;
    int wcol = w * 16;
    int ar = tid >> 5, ap = tid & 31;     // A staging: 16 rows x 32 chunks of 8B
    int wn = tid >> 2, wq = tid & 3;      // W staging: 128 cols x 4 chunks of 64B

    f32x4 acc = {0, 0, 0, 0};

    uint2 aR = *((const uint2*)(ch1b + ((size_t)(b * N1 + knnr[ar][0])) * COUT) + ap);
    uint4 wR[4];
    {
        const uint4* s4 = (const uint4*)(W2b + (size_t)wn * 2048 + wq * 32);
        wR[0] = s4[0]; wR[1] = s4[1]; wR[2] = s4[2]; wR[3] = s4[3];
    }
    for (int kn = 0; kn < 16; ++kn) {
        *(uint2*)&As[ar][ap * 4] = aR;
        uint4* d4 = (uint4*)&Ws[wn][wq * 32];
        d4[0] = wR[0]; d4[1] = wR[1]; d4[2] = wR[2]; d4[3] = wR[3];
        __syncthreads();
        if (kn < 15) {
            aR = *((const uint2*)(ch1b + ((size_t)(b * N1 + knnr[ar][kn + 1])) * COUT) + ap);
            const uint4* s4 = (const uint4*)(W2b + (size_t)wn * 2048 + (kn + 1) * 128 + wq * 32);
            wR[0] = s4[0]; wR[1] = s4[1]; wR[2] = s4[2]; wR[3] = s4[3];
        }
#pragma unroll
        for (int ks = 0; ks < 4; ++ks) {
            bf16x8 af = *(const bf16x8*)&As[l15][ks * 32 + quad * 8];
            bf16x8 bfr = *(const bf16x8*)&Ws[wcol + l15][ks * 32 + quad * 8];
            acc = __builtin_amdgcn_mfma_f32_16x16x32_bf16(af, bfr, acc, 0, 0, 0);
        }
        __syncthreads();
    }

    float x[4], s[4], ss[4];
#pragma unroll
    for (int reg = 0; reg < 4; ++reg) {
        int col = wcol + l15;
        float v = acc[reg] + cb[col];
        x[reg] = v; s[reg] = v; ss[reg] = v * v;
    }
#pragma unroll
    for (int m = 1; m < 16; m <<= 1)
#pragma unroll
        for (int reg = 0; reg < 4; ++reg) {
            s[reg] += __shfl_xor(s[reg], m, 64);
            ss[reg] += __shfl_xor(ss[reg], m, 64);
        }
    if (l15 == 0) {
#pragma unroll
        for (int reg = 0; reg < 4; ++reg) {
            red[quad * 4 + reg][w][0] = s[reg];
            red[quad * 4 + reg][w][1] = ss[reg];
        }
    }
    __syncthreads();
#pragma unroll
    for (int reg = 0; reg < 4; ++reg) {
        int row = quad * 4 + reg;
        float S = 0.f, SS = 0.f;
#pragma unroll
        for (int t = 0; t < 8; ++t) { S += red[row][t][0]; SS += red[row][t][1]; }
        float mu = S * (1.f / 128.f);
        float var = fmaxf(SS * (1.f / 128.f) - mu * mu, 0.f);
        float rs = 1.f / sqrtf(var + 1e-5f);
        int col = wcol + l15;
        int i = ibase + row;
        float y = (x[reg] - mu) * rs * cg[col] + cbe[col];
        float sl = y / (1.f + __expf(-y));
        float rv = bf2f(res1b[((size_t)(b * N1 + 2 * i)) * COUT + col]);
        ch_out[((size_t)(b * N2 + i)) * COUT + col] = sl + rv;
    }
}

extern "C" void kernel_launch(void* const* d_in, const int* in_sizes, int n_in,
                              void* d_out, int out_size, void* d_ws, size_t ws_size,
                              hipStream_t stream) {
    const float* pos0 = (const float*)d_in[0];
    const float* ch0  = (const float*)d_in[1];
    const float* W1   = (const float*)d_in[2];
    const float* b1   = (const float*)d_in[3];
    const float* Wres = (const float*)d_in[4];
    const float* bres = (const float*)d_in[5];
    const float* W2   = (const float*)d_in[6];
    const float* b2   = (const float*)d_in[7];
    const float* g1   = (const float*)d_in[8];
    const float* be1  = (const float*)d_in[9];
    const float* g2   = (const float*)d_in[10];
    const float* be2  = (const float*)d_in[11];
    float* out = (float*)d_out;

    char* ws = (char*)d_ws;
    int*  knn1  = (int*)(ws);                      // 524288
    int*  knn2  = (int*)(ws + 524288);             // 262144
    u16*  ch0b  = (u16*)(ws + 786432);             // 2097152
    u16*  W1b   = (u16*)(ws + 2883584);            // 262144
    u16*  W2b   = (u16*)(ws + 3145728);            // 524288
    u16*  Wresb = (u16*)(ws + 3670016);            // 16384
    u16*  ch1b  = (u16*)(ws + 3686400);            // 2097152
    u16*  res1b = (u16*)(ws + 5783552);            // 2097152
    uint4* sortedA = (uint4*)(ws + 7880704);       // 262144 (2 x 8192 x 16B)
    uint4* sortedB = (uint4*)(ws + 8142848);       // 131072 (2 x 4096 x 16B)
    u32*  rankA = (u32*)(ws + 8273920);            // 65536
    u32*  rankB = (u32*)(ws + 8339456);            // 32768  (total ~8.0 MB)

    float* pos_out = out;          // [2,2048,3] fp32
    float* ch_out  = out + 12288;  // [2,2048,128] fp32

    sort_prep_kernel<<<192, 1024, 0, stream>>>(pos0, ch0, W1, W2, Wres,
                                               sortedA, rankA, sortedB, rankB,
                                               ch0b, W1b, W2b, Wresb, pos_out);
    knn_prep_kernel<<<2048, 256, 0, stream>>>(pos0, sortedA, rankA, knn1);
    conv1_knn2_kernel<<<1536, 256, 0, stream>>>(ch0b, knn1, W1b, Wresb, b1, bres, g1, be1,
                                                ch1b, res1b, pos0, sortedB, rankB, knn2);
    conv2_kernel<<<256, 512, 0, stream>>>(ch1b, knn2, W2b, b2, g2, be2, res1b, ch_out);
}

// Round 4
// 189.054 us; speedup vs baseline: 1.3309x; 1.1985x over previous
//
#include <hip/hip_runtime.h>
#include <cstdint>
#include <cstddef>

using u16 = unsigned short;
using u32 = unsigned int;
using u64 = unsigned long long;

typedef short bf16x8 __attribute__((ext_vector_type(8)));
typedef float f32x4 __attribute__((ext_vector_type(4)));

constexpr int N0 = 8192;
constexpr int N1 = 4096;
constexpr int N2 = 2048;
constexpr int COUT = 128;
constexpr int KNB = 16;

__device__ __forceinline__ float bf2f(u16 v) { return __uint_as_float(((u32)v) << 16); }
__device__ __forceinline__ u16 f2bf(float f) {  // round-to-nearest-even
    u32 u = __float_as_uint(f);
    return (u16)((u + 0x7fffu + ((u >> 16) & 1u)) >> 16);
}
__device__ __forceinline__ void cvt8(const float* __restrict__ src, u16* __restrict__ dst, int e) {
    float t0[8];
    *(float4*)t0 = *(const float4*)(src + e);
    *(float4*)(t0 + 4) = *(const float4*)(src + e + 4);
    u16 o[8];
#pragma unroll
    for (int q = 0; q < 8; ++q) o[q] = f2bf(t0[q]);
    *(uint4*)(dst + e) = *(uint4*)o;
}

// Distances must match the np reference bit-exactly: no FMA contraction, sequential sum.
__device__ __forceinline__ float dist2s(float cx, float cy, float cz,
                                        float px, float py, float pz) {
#pragma clang fp contract(off)
    float dx = cx - px;
    float dy = cy - py;
    float dz = cz - pz;
    float s = dx * dx;
    s = s + dy * dy;
    s = s + dz * dz;
    return s;
}

// ---- DPP cross-lane helpers (VALU pipe, no LDS traffic) ----
template <int CTRL>
__device__ __forceinline__ u64 dpp64(u64 v) {
    int lo = (int)(u32)v, hi = (int)(u32)(v >> 32);
    int plo = __builtin_amdgcn_update_dpp(0, lo, CTRL, 0xF, 0xF, true);
    int phi = __builtin_amdgcn_update_dpp(0, hi, CTRL, 0xF, 0xF, true);
    return (((u64)(u32)phi) << 32) | (u32)plo;
}
// row_shr:1 with bound_ctrl=1: lane L gets lane L-1; lane 0 of each 16-row gets 0.
__device__ __forceinline__ u64 dpp_prev_u64(u64 v) { return dpp64<0x111>(v); }

// wave-uniform broadcast via v_readlane (scalar result, no ds_bpermute on the chain)
__device__ __forceinline__ u32 rdlane(u32 v, int l) {
    return (u32)__builtin_amdgcn_readlane((int)v, l);
}

// ---------------- KNN scan, one wave, TWO centers, 128 candidates/step (2 per lane).
// Sorted-16 list in lanes 0..15 as u64 (d2_bits<<32)|idx — exact order + low-index tie-break.
// PROVEN at R1 (221 us, passed). Candidate broadcast + cut update = v_readlane; cut test is
// a SUPERSET filter (u32 d<=cut); exact u64 compare in insert makes stale extras no-ops.
template <int PSTRIDE>
__device__ __forceinline__ void knn_scan(const float* __restrict__ P,
                                         int c0row, int c1row, int cnt,
                                         int lane, u64& rk0, u64& rk1) {
    const float* c0p = P + (size_t)c0row * PSTRIDE;
    const float* c1p = P + (size_t)c1row * PSTRIDE;
    float c0x = c0p[0], c0y = c0p[1], c0z = c0p[2];
    float c1x = c1p[0], c1y = c1p[1], c1z = c1p[2];

    u64 key0, key1;
    {   // warm start: bitonic-sort first 64 points (xor 1/2/8 via DPP)
        const float* pp = P + (size_t)lane * PSTRIDE;
        float px = pp[0], py = pp[1], pz = pp[2];
        u64 k0 = (((u64)__float_as_uint(dist2s(c0x, c0y, c0z, px, py, pz))) << 32) | (u32)lane;
        u64 k1 = (((u64)__float_as_uint(dist2s(c1x, c1y, c1z, px, py, pz))) << 32) | (u32)lane;
#pragma unroll
        for (int kk = 2; kk <= 64; kk <<= 1)
#pragma unroll
            for (int jj = kk >> 1; jj > 0; jj >>= 1) {
                u64 o0, o1;
                if (jj == 1)      { o0 = dpp64<0xB1>(k0);  o1 = dpp64<0xB1>(k1); }
                else if (jj == 2) { o0 = dpp64<0x4E>(k0);  o1 = dpp64<0x4E>(k1); }
                else if (jj == 8) { o0 = dpp64<0x128>(k0); o1 = dpp64<0x128>(k1); }
                else              { o0 = __shfl_xor(k0, jj, 64); o1 = __shfl_xor(k1, jj, 64); }
                bool keepmin = (((lane & jj) == 0) == ((lane & kk) == 0));
                k0 = keepmin ? ((o0 < k0) ? o0 : k0) : ((o0 > k0) ? o0 : k0);
                k1 = keepmin ? ((o1 < k1) ? o1 : k1) : ((o1 > k1) ? o1 : k1);
            }
        key0 = k0; key1 = k1;
    }
    u32 cut0 = rdlane((u32)(key0 >> 32), 15);
    u32 cut1 = rdlane((u32)(key1 >> 32), 15);

    {   // half-step: candidates [64,128), one per lane
        const float* pp = P + (size_t)(64 + lane) * PSTRIDE;
        float px = pp[0], py = pp[1], pz = pp[2];
        u32 d0 = __float_as_uint(dist2s(c0x, c0y, c0z, px, py, pz));
        u32 d1 = __float_as_uint(dist2s(c1x, c1y, c1z, px, py, pz));
        u64 ball0 = __ballot(d0 <= cut0);
        u64 ball1 = __ballot(d1 <= cut1);
        while (ball0 | ball1) {
            if (ball0) {
                int src = __ffsll((unsigned long long)ball0) - 1;
                ball0 &= ball0 - 1;
                u64 nk = (((u64)rdlane(d0, src)) << 32) | (u32)(64 + src);
                u64 prev = dpp_prev_u64(key0);
                key0 = (nk < key0) ? ((nk < prev) ? prev : nk) : key0;
            }
            if (ball1) {
                int src = __ffsll((unsigned long long)ball1) - 1;
                ball1 &= ball1 - 1;
                u64 nk = (((u64)rdlane(d1, src)) << 32) | (u32)(64 + src);
                u64 prev = dpp_prev_u64(key1);
                key1 = (nk < key1) ? ((nk < prev) ? prev : nk) : key1;
            }
        }
        cut0 = rdlane((u32)(key0 >> 32), 15);
        cut1 = rdlane((u32)(key1 >> 32), 15);
    }

    // main loop: 128 candidates/step (2 per lane), starting at 128.
    constexpr int STEPF = 128 * PSTRIDE;
    int nstep = (cnt - 128) >> 7;
    const float* cur = P + (size_t)(128 + 2 * lane) * PSTRIDE;
    float ax = cur[0], ay = cur[1], az = cur[2];
    float bx = cur[PSTRIDE], by = cur[PSTRIDE + 1], bz = cur[PSTRIDE + 2];
    for (int s = 0; s < nstep; ++s) {
        float cax = ax, cay = ay, caz = az, cbx = bx, cby = by, cbz = bz;
        cur += STEPF;
        if (s + 1 < nstep) {
            ax = cur[0]; ay = cur[1]; az = cur[2];
            bx = cur[PSTRIDE]; by = cur[PSTRIDE + 1]; bz = cur[PSTRIDE + 2];
        }
        int sb = 128 + (s << 7);
        u32 da0 = __float_as_uint(dist2s(c0x, c0y, c0z, cax, cay, caz));
        u32 da1 = __float_as_uint(dist2s(c1x, c1y, c1z, cax, cay, caz));
        u32 db0 = __float_as_uint(dist2s(c0x, c0y, c0z, cbx, cby, cbz));
        u32 db1 = __float_as_uint(dist2s(c1x, c1y, c1z, cbx, cby, cbz));
        u64 ba0 = __ballot(da0 <= cut0);
        u64 bb0 = __ballot(db0 <= cut0);
        u64 ba1 = __ballot(da1 <= cut1);
        u64 bb1 = __ballot(db1 <= cut1);
        while (ba0 | bb0 | ba1 | bb1) {   // two independent key chains, 4 ballot streams
            if (ba0) {
                int src = __ffsll((unsigned long long)ba0) - 1;
                ba0 &= ba0 - 1;
                u64 nk = (((u64)rdlane(da0, src)) << 32) | (u32)(sb + 2 * src);
                u64 prev = dpp_prev_u64(key0);
                key0 = (nk < key0) ? ((nk < prev) ? prev : nk) : key0;
            }
            if (ba1) {
                int src = __ffsll((unsigned long long)ba1) - 1;
                ba1 &= ba1 - 1;
                u64 nk = (((u64)rdlane(da1, src)) << 32) | (u32)(sb + 2 * src);
                u64 prev = dpp_prev_u64(key1);
                key1 = (nk < key1) ? ((nk < prev) ? prev : nk) : key1;
            }
            if (bb0) {
                int src = __ffsll((unsigned long long)bb0) - 1;
                bb0 &= bb0 - 1;
                u64 nk = (((u64)rdlane(db0, src)) << 32) | (u32)(sb + 2 * src + 1);
                u64 prev = dpp_prev_u64(key0);
                key0 = (nk < key0) ? ((nk < prev) ? prev : nk) : key0;
            }
            if (bb1) {
                int src = __ffsll((unsigned long long)bb1) - 1;
                bb1 &= bb1 - 1;
                u64 nk = (((u64)rdlane(db1, src)) << 32) | (u32)(sb + 2 * src + 1);
                u64 prev = dpp_prev_u64(key1);
                key1 = (nk < key1) ? ((nk < prev) ? prev : nk) : key1;
            }
        }
        cut0 = rdlane((u32)(key0 >> 32), 15);
        cut1 = rdlane((u32)(key1 >> 32), 15);
    }
    rk0 = key0; rk1 = key1;
}

// ---------------- dispatch 1: knn1 (1024 blk) + prep (752 blk) — R1 verbatim -------
__global__ __launch_bounds__(256)
void knn_prep_kernel(const float* __restrict__ pos0, const float* __restrict__ ch0,
                     const float* __restrict__ W1, const float* __restrict__ W2,
                     const float* __restrict__ Wres,
                     int* __restrict__ knn1,
                     u16* __restrict__ ch0b, u16* __restrict__ W1b,
                     u16* __restrict__ W2b, u16* __restrict__ Wresb,
                     float* __restrict__ pos_out) {
    int blk = blockIdx.x, tid = threadIdx.x;
    int w = tid >> 6, lane = tid & 63;
    if (blk < 1024) {
        int wave = blk * 4 + w;
        int batch = wave >> 11, pj = wave & 2047;
        const float* P = pos0 + (size_t)batch * N0 * 3;
        u64 key0, key1;
        knn_scan<3>(P, 4 * pj, 4 * pj + 2, N0, lane, key0, key1);
        if (lane < 16) {
            knn1[((size_t)(batch * N1 + 2 * pj)) * KNB + lane] = (int)(u32)key0;
            knn1[((size_t)(batch * N1 + 2 * pj + 1)) * KNB + lane] = (int)(u32)key1;
        }
    } else if (blk < 1536) {          // ch0 -> bf16 (1,048,576 elems)
        cvt8(ch0, ch0b, ((blk - 1024) * 256 + tid) * 8);
    } else if (blk < 1600) {          // W1 -> bf16 (131,072)
        cvt8(W1, W1b, ((blk - 1536) * 256 + tid) * 8);
    } else if (blk < 1728) {          // W2 -> bf16 (262,144)
        cvt8(W2, W2b, ((blk - 1600) * 256 + tid) * 8);
    } else if (blk < 1760) {          // Wres[c][o] -> Wresb[o][c] bf16 (8192 elems)
        int t = (blk - 1728) * 256 + tid;
        int o = t >> 6, c = t & 63;
        Wresb[o * 64 + c] = f2bf(Wres[(size_t)c * COUT + o]);
    } else {                          // pos_out copy: 4096 rows (16 blocks)
        int t = (blk - 1760) * 256 + tid;
        int b = t >> 11, r = t & 2047;
        const float* s = pos0 + ((size_t)(b * N0 + r * 4)) * 3;
        float* d = pos_out + ((size_t)(b * N2 + r)) * 3;
        d[0] = s[0]; d[1] = s[1]; d[2] = s[2];
    }
}

// ---------------- dispatch 2: conv1 W-direct (512 blk) + knn2 brute (512 blk) ------
// conv1 v2: weights load straight global->VGPR as MFMA B-fragments (per-lane address
// W1b[col*1024 + kn*64 + ks*32 + quad*8]; a wave's 4 quads x 2 ks tile 128B/col, lines
// fully consumed). Only the gathered A-tile is LDS-staged, double-buffered, ONE barrier
// per K-chunk. W register-prefetched one chunk ahead.
__global__ __launch_bounds__(256)
void conv1_knn2_kernel(const u16* __restrict__ ch0b, const int* __restrict__ knn1,
                       const u16* __restrict__ W1b, const u16* __restrict__ Wresb,
                       const float* __restrict__ b1, const float* __restrict__ bres,
                       const float* __restrict__ g1, const float* __restrict__ be1,
                       u16* __restrict__ ch1b, u16* __restrict__ res1b,
                       const float* __restrict__ pos0, int* __restrict__ knn2) {
    __shared__ u16 As[2][16][72];     // double-buffered A tile: 16 rows x 64 bf16 (+8 pad)
    __shared__ int knnr[16][16];
    __shared__ float red[16][4][2];
    __shared__ float cb[128], cg[128], cbe[128], cbr[128];

    int blk = blockIdx.x, tid = threadIdx.x;

    if (blk >= 512) {
        // knn2: brute scan over level-1 rows (stride 6), 2 centers/wave — R1 verbatim
        int w = tid >> 6, lane = tid & 63;
        int wave = (blk - 512) * 4 + w;
        int batch = wave >> 10, pj = wave & 1023;
        const float* P = pos0 + (size_t)batch * N0 * 3;
        u64 key0, key1;
        knn_scan<6>(P, 4 * pj, 4 * pj + 2, N1, lane, key0, key1);
        if (lane < 16) {
            knn2[((size_t)(batch * N2 + 2 * pj)) * KNB + lane] = (int)(u32)key0;
            knn2[((size_t)(batch * N2 + 2 * pj + 1)) * KNB + lane] = (int)(u32)key1;
        }
        return;
    }

    int b = blk >> 8, g = blk & 255;
    int jbase = g * 16;

    if (tid < 128) { cb[tid] = b1[tid]; cg[tid] = g1[tid]; cbe[tid] = be1[tid]; cbr[tid] = bres[tid]; }
    {   // 256 knn ints, 1 per thread
        int r = tid >> 4, k = tid & 15;
        knnr[r][k] = knn1[((size_t)(b * N1 + jbase + r)) * KNB + k];
    }
    __syncthreads();

    int w = tid >> 6, lane = tid & 63, quad = lane >> 4, l15 = lane & 15;
    int wcol = w * 32;
    int ar = tid >> 4, ap = tid & 15;     // A staging: 16 rows x 16 chunks of 8B

    f32x4 acc[2] = {{0,0,0,0},{0,0,0,0}};
    f32x4 racc[2] = {{0,0,0,0},{0,0,0,0}};

    // per-lane W fragment bases (cols wcol+l15 and wcol+16+l15)
    const u16* w0base = W1b + (size_t)(wcol + l15) * 1024 + quad * 8;
    const u16* w1base = W1b + (size_t)(wcol + 16 + l15) * 1024 + quad * 8;

    // prologue: prefetch chunk 0
    uint2 aR = *((const uint2*)(ch0b + ((size_t)(b * N0 + knnr[ar][0])) * 64) + ap);
    uint4 wcur[4] = { *(const uint4*)w0base, *(const uint4*)(w0base + 32),
                      *(const uint4*)w1base, *(const uint4*)(w1base + 32) };

    int pb = 0;
    for (int kn = 0; kn < 17; ++kn) {     // 16 neighbor chunks + 1 residual chunk
        *(uint2*)&As[pb][ar][ap * 4] = aR;
        __syncthreads();
        uint4 wnxt[4];
        if (kn < 16) {  // prefetch next chunk (kn==15 -> residual sources)
            int nidx = (kn < 15) ? knnr[ar][kn + 1] : 2 * (jbase + ar);
            aR = *((const uint2*)(ch0b + ((size_t)(b * N0 + nidx)) * 64) + ap);
            if (kn < 15) {
                const u16* p0 = w0base + (kn + 1) * 64;
                const u16* p1 = w1base + (kn + 1) * 64;
                wnxt[0] = *(const uint4*)p0; wnxt[1] = *(const uint4*)(p0 + 32);
                wnxt[2] = *(const uint4*)p1; wnxt[3] = *(const uint4*)(p1 + 32);
            } else {
                const u16* p0 = Wresb + (size_t)(wcol + l15) * 64 + quad * 8;
                const u16* p1 = Wresb + (size_t)(wcol + 16 + l15) * 64 + quad * 8;
                wnxt[0] = *(const uint4*)p0; wnxt[1] = *(const uint4*)(p0 + 32);
                wnxt[2] = *(const uint4*)p1; wnxt[3] = *(const uint4*)(p1 + 32);
            }
        }
        if (kn < 16) {
#pragma unroll
            for (int ks = 0; ks < 2; ++ks) {
                bf16x8 af = *(const bf16x8*)&As[pb][l15][ks * 32 + quad * 8];
                acc[0] = __builtin_amdgcn_mfma_f32_16x16x32_bf16(af, *(const bf16x8*)&wcur[ks], acc[0], 0, 0, 0);
                acc[1] = __builtin_amdgcn_mfma_f32_16x16x32_bf16(af, *(const bf16x8*)&wcur[2 + ks], acc[1], 0, 0, 0);
            }
        } else {
#pragma unroll
            for (int ks = 0; ks < 2; ++ks) {
                bf16x8 af = *(const bf16x8*)&As[pb][l15][ks * 32 + quad * 8];
                racc[0] = __builtin_amdgcn_mfma_f32_16x16x32_bf16(af, *(const bf16x8*)&wcur[ks], racc[0], 0, 0, 0);
                racc[1] = __builtin_amdgcn_mfma_f32_16x16x32_bf16(af, *(const bf16x8*)&wcur[2 + ks], racc[1], 0, 0, 0);
            }
        }
        if (kn < 16) {
            wcur[0] = wnxt[0]; wcur[1] = wnxt[1]; wcur[2] = wnxt[2]; wcur[3] = wnxt[3];
        }
        pb ^= 1;
    }

    // epilogue: bias + LN(+SiLU) on conv acc; bias on residual; both stored bf16
    float x[2][4], s[4] = {0,0,0,0}, ss[4] = {0,0,0,0};
#pragma unroll
    for (int reg = 0; reg < 4; ++reg)
#pragma unroll
        for (int nt = 0; nt < 2; ++nt) {
            int col = wcol + nt * 16 + l15;
            float v = acc[nt][reg] + cb[col];
            x[nt][reg] = v;
            s[reg] += v; ss[reg] += v * v;
        }
#pragma unroll
    for (int m = 1; m < 16; m <<= 1)
#pragma unroll
        for (int reg = 0; reg < 4; ++reg) {
            s[reg] += __shfl_xor(s[reg], m, 64);
            ss[reg] += __shfl_xor(ss[reg], m, 64);
        }
    if (l15 == 0) {
#pragma unroll
        for (int reg = 0; reg < 4; ++reg) {
            red[quad * 4 + reg][w][0] = s[reg];
            red[quad * 4 + reg][w][1] = ss[reg];
        }
    }
    __syncthreads();
    float mu[4], rs[4];
#pragma unroll
    for (int reg = 0; reg < 4; ++reg) {
        int row = quad * 4 + reg;
        float S = red[row][0][0] + red[row][1][0] + red[row][2][0] + red[row][3][0];
        float SS = red[row][0][1] + red[row][1][1] + red[row][2][1] + red[row][3][1];
        mu[reg] = S * (1.f / 128.f);
        float var = fmaxf(SS * (1.f / 128.f) - mu[reg] * mu[reg], 0.f);
        rs[reg] = 1.f / sqrtf(var + 1e-5f);
    }
#pragma unroll
    for (int nt = 0; nt < 2; ++nt)
#pragma unroll
        for (int reg = 0; reg < 4; ++reg) {
            int col = wcol + nt * 16 + l15;
            int row = quad * 4 + reg;
            size_t off = ((size_t)(b * N1 + jbase + row)) * COUT + col;
            float y = (x[nt][reg] - mu[reg]) * rs[reg] * cg[col] + cbe[col];
            ch1b[off] = f2bf(y / (1.f + __expf(-y)));
            res1b[off] = f2bf(racc[nt][reg] + cbr[col]);
        }
}

// ---------------- dispatch 3: conv2 W-direct, K=2048, 512 thr (8 waves), M=16 ------
__global__ __launch_bounds__(512)
void conv2_kernel(const u16* __restrict__ ch1b, const int* __restrict__ knn2,
                  const u16* __restrict__ W2b, const float* __restrict__ b2,
                  const float* __restrict__ g2, const float* __restrict__ be2,
                  const u16* __restrict__ res1b, float* __restrict__ ch_out) {
    __shared__ u16 As[2][16][136];    // double-buffered A tile: 16 rows x 128 bf16 (+8 pad)
    __shared__ int knnr[16][16];
    __shared__ float red[16][8][2];
    __shared__ float cb[128], cg[128], cbe[128];

    int tid = threadIdx.x;            // 0..511
    int b = blockIdx.x >> 7, g = blockIdx.x & 127;
    int ibase = g * 16;

    if (tid < 128) { cb[tid] = b2[tid]; cg[tid] = g2[tid]; cbe[tid] = be2[tid]; }
    if (tid < 256) {
        int r = tid >> 4, k = tid & 15;
        knnr[r][k] = knn2[((size_t)(b * N2 + ibase + r)) * KNB + k];
    }
    __syncthreads();

    int w = tid >> 6, lane = tid & 63, quad = lane >> 4, l15 = lane & 15;
    int wcol = w * 16;
    int ar = tid >> 5, ap = tid & 31;     // A staging: 16 rows x 32 chunks of 8B

    f32x4 acc = {0, 0, 0, 0};

    // per-lane W fragment base (col wcol+l15); frag(ks) at kn: base + kn*128 + ks*32
    const u16* wbase = W2b + (size_t)(wcol + l15) * 2048 + quad * 8;

    uint2 aR = *((const uint2*)(ch1b + ((size_t)(b * N1 + knnr[ar][0])) * COUT) + ap);
    uint4 wcur[4] = { *(const uint4*)wbase, *(const uint4*)(wbase + 32),
                      *(const uint4*)(wbase + 64), *(const uint4*)(wbase + 96) };

    int pb = 0;
    for (int kn = 0; kn < 16; ++kn) {
        *(uint2*)&As[pb][ar][ap * 4] = aR;
        __syncthreads();
        uint4 wnxt[4];
        if (kn < 15) {
            aR = *((const uint2*)(ch1b + ((size_t)(b * N1 + knnr[ar][kn + 1])) * COUT) + ap);
            const u16* p = wbase + (kn + 1) * 128;
            wnxt[0] = *(const uint4*)p;        wnxt[1] = *(const uint4*)(p + 32);
            wnxt[2] = *(const uint4*)(p + 64); wnxt[3] = *(const uint4*)(p + 96);
        }
#pragma unroll
        for (int ks = 0; ks < 4; ++ks) {
            bf16x8 af = *(const bf16x8*)&As[pb][l15][ks * 32 + quad * 8];
            acc = __builtin_amdgcn_mfma_f32_16x16x32_bf16(af, *(const bf16x8*)&wcur[ks], acc, 0, 0, 0);
        }
        if (kn < 15) {
            wcur[0] = wnxt[0]; wcur[1] = wnxt[1]; wcur[2] = wnxt[2]; wcur[3] = wnxt[3];
        }
        pb ^= 1;
    }

    float x[4], s[4], ss[4];
#pragma unroll
    for (int reg = 0; reg < 4; ++reg) {
        int col = wcol + l15;
        float v = acc[reg] + cb[col];
        x[reg] = v; s[reg] = v; ss[reg] = v * v;
    }
#pragma unroll
    for (int m = 1; m < 16; m <<= 1)
#pragma unroll
        for (int reg = 0; reg < 4; ++reg) {
            s[reg] += __shfl_xor(s[reg], m, 64);
            ss[reg] += __shfl_xor(ss[reg], m, 64);
        }
    if (l15 == 0) {
#pragma unroll
        for (int reg = 0; reg < 4; ++reg) {
            red[quad * 4 + reg][w][0] = s[reg];
            red[quad * 4 + reg][w][1] = ss[reg];
        }
    }
    __syncthreads();
#pragma unroll
    for (int reg = 0; reg < 4; ++reg) {
        int row = quad * 4 + reg;
        float S = 0.f, SS = 0.f;
#pragma unroll
        for (int t = 0; t < 8; ++t) { S += red[row][t][0]; SS += red[row][t][1]; }
        float mu = S * (1.f / 128.f);
        float var = fmaxf(SS * (1.f / 128.f) - mu * mu, 0.f);
        float rs = 1.f / sqrtf(var + 1e-5f);
        int col = wcol + l15;
        int i = ibase + row;
        float y = (x[reg] - mu) * rs * cg[col] + cbe[col];
        float sl = y / (1.f + __expf(-y));
        float rv = bf2f(res1b[((size_t)(b * N1 + 2 * i)) * COUT + col]);
        ch_out[((size_t)(b * N2 + i)) * COUT + col] = sl + rv;
    }
}

extern "C" void kernel_launch(void* const* d_in, const int* in_sizes, int n_in,
                              void* d_out, int out_size, void* d_ws, size_t ws_size,
                              hipStream_t stream) {
    const float* pos0 = (const float*)d_in[0];
    const float* ch0  = (const float*)d_in[1];
    const float* W1   = (const float*)d_in[2];
    const float* b1   = (const float*)d_in[3];
    const float* Wres = (const float*)d_in[4];
    const float* bres = (const float*)d_in[5];
    const float* W2   = (const float*)d_in[6];
    const float* b2   = (const float*)d_in[7];
    const float* g1   = (const float*)d_in[8];
    const float* be1  = (const float*)d_in[9];
    const float* g2   = (const float*)d_in[10];
    const float* be2  = (const float*)d_in[11];
    float* out = (float*)d_out;

    char* ws = (char*)d_ws;
    int*  knn1  = (int*)(ws);                      // 524288
    int*  knn2  = (int*)(ws + 524288);             // 262144
    u16*  ch0b  = (u16*)(ws + 786432);             // 2097152
    u16*  W1b   = (u16*)(ws + 2883584);            // 262144
    u16*  W2b   = (u16*)(ws + 3145728);            // 524288
    u16*  Wresb = (u16*)(ws + 3670016);            // 16384
    u16*  ch1b  = (u16*)(ws + 3686400);            // 2097152
    u16*  res1b = (u16*)(ws + 5783552);            // 2097152  (total ~7.9 MB)

    float* pos_out = out;          // [2,2048,3] fp32
    float* ch_out  = out + 12288;  // [2,2048,128] fp32

    knn_prep_kernel<<<1776, 256, 0, stream>>>(pos0, ch0, W1, W2, Wres,
                                              knn1, ch0b, W1b, W2b, Wresb, pos_out);
    conv1_knn2_kernel<<<1024, 256, 0, stream>>>(ch0b, knn1, W1b, Wresb, b1, bres, g1, be1,
                                                ch1b, res1b, pos0, knn2);
    conv2_kernel<<<256, 512, 0, stream>>>(ch1b, knn2, W2b, b2, g2, be2, res1b, ch_out);
}